// Round 2
// baseline (589.882 us; speedup 1.0000x reference)
//
#include <hip/hip_runtime.h>
#include <math.h>

#define BB 16
#define NN 4096
#define DD 128
#define KK 1024
#define NPTS (BB*NN)

// ---------------- kernel 0: centroid squared norms (double accum) ----------------
__global__ void cnorm_kernel(const float* __restrict__ c, float* __restrict__ cnorm) {
    int k = blockIdx.x * 256 + threadIdx.x;
    if (k >= KK) return;
    const float* row = c + k * DD;
    double s = 0.0;
#pragma unroll
    for (int d = 0; d < DD; ++d) { double v = (double)row[d]; s += v * v; }
    cnorm[k] = (float)s;
}

// component extractor with compile-time index (keeps xr4 fully statically indexed -> registers)
#define XR(i) (((i)&3)==0 ? xr4[(i)>>2].x : ((i)&3)==1 ? xr4[(i)>>2].y : \
               ((i)&3)==2 ? xr4[(i)>>2].z : xr4[(i)>>2].w)

// ---------------- kernel 1: nearest-centroid assignment ----------------
// Block: 256 threads = 4 waves. Waves (0,1) own points [0,64), waves (2,3) own [64,128)
// of the block's 128-point slice; within a pair, wave kh=0 scans k in [0,512),
// kh=1 scans [512,1024) (split-K for 2 waves/SIMD of TLP).
// Each lane holds its point's full x row in 32 float4 VGPRs (loaded once,
// per-lane-sequential -> L1-coalesced). Centroid values are wave-uniform ->
// compiler emits s_load into SGPRs (SMEM pipe, parallel to VALU). Inner loop is
// pure v_fmac_f32 with SGPR src0, 4 independent chains -> VALU-issue-bound.
// No LDS in the inner loop at all.
__launch_bounds__(256, 2)
__global__ void assign_kernel(const float* __restrict__ x, const float* __restrict__ cent,
                              const float* __restrict__ cnorm,
                              float* __restrict__ min_d, int* __restrict__ nearest) {
    __shared__ float lv[128][2];
    __shared__ int   lk[128][2];

    const int tid = threadIdx.x;
    const int lane = tid & 63;
    const int wid = __builtin_amdgcn_readfirstlane(tid >> 6);  // wave-uniform for scalarization
    const int g = wid >> 1;    // point group within block
    const int kh = wid & 1;    // k half
    const int p = blockIdx.x * 128 + g * 64 + lane;

    // x row -> registers (32 x float4)
    float4 xr4[32];
    const float4* xsrc = (const float4*)(x + (size_t)p * DD);
#pragma unroll
    for (int i = 0; i < 32; ++i) xr4[i] = xsrc[i];

    float best = INFINITY;
    int bestk = 0;

    const int kbeg = kh * (KK / 2);
    const int kend = kbeg + KK / 2;
    for (int k0 = kbeg; k0 < kend; k0 += 4) {
        float acc[4] = {0.f, 0.f, 0.f, 0.f};
#pragma unroll
        for (int dc = 0; dc < DD; dc += 16) {
            float cc[4][16];  // wave-uniform -> SGPRs via s_load
#pragma unroll
            for (int j = 0; j < 4; ++j)
#pragma unroll
                for (int d = 0; d < 16; ++d)
                    cc[j][d] = cent[(size_t)(k0 + j) * DD + dc + d];
#pragma unroll
            for (int d = 0; d < 16; ++d) {
                const float xv = XR(dc + d);
#pragma unroll
                for (int j = 0; j < 4; ++j)
                    acc[j] = fmaf(xv, cc[j][d], acc[j]);
            }
        }
#pragma unroll
        for (int j = 0; j < 4; ++j) {
            float val = cnorm[k0 + j] - 2.0f * acc[j];  // same expr/contraction as round 1
            if (val < best) { best = val; bestk = k0 + j; }  // strict <: first-min, k ascending
        }
    }

    // merge the two k-halves (kh=0 ks are all smaller -> strict < keeps numpy tie-break)
    lv[g * 64 + lane][kh] = best;
    lk[g * 64 + lane][kh] = bestk;
    __syncthreads();
    if (kh == 0) {
        float v1 = lv[g * 64 + lane][1];
        int k1v = lk[g * 64 + lane][1];
        if (v1 < best) { best = v1; bestk = k1v; }
        // ||x||^2 in double (bias-free; only shifts min_d, not argmin)
        double xn = 0.0;
#pragma unroll
        for (int i = 0; i < 32; ++i) {
            float4 v = xr4[i];
            xn += (double)v.x * v.x + (double)v.y * v.y + (double)v.z * v.z + (double)v.w * v.w;
        }
        float sq = (float)xn + best;
        min_d[p] = sqrtf(fmaxf(sq, 0.f));
        nearest[p] = bestk;
    }
}

// ---------------- kernel 2: per-batch stats + histogram + normalize ----------------
__global__ void finalize_kernel(const float* __restrict__ min_d, const int* __restrict__ nearest,
                                const float* __restrict__ weights, float* __restrict__ out) {
    __shared__ float red[256];
    __shared__ int hist[KK];
    __shared__ float bc[2];  // mean, thr
    const int b = blockIdx.x;
    const int tid = threadIdx.x;
    const float* md = min_d + (size_t)b * NN;
    const int* nr = nearest + (size_t)b * NN;

    // pass A: mean (two-pass std to match numpy's numerics)
    float s = 0.f;
#pragma unroll
    for (int j = 0; j < NN / 256; ++j) s += md[tid + 256 * j];
    red[tid] = s;
    __syncthreads();
    for (int off = 128; off > 0; off >>= 1) {
        if (tid < off) red[tid] += red[tid + off];
        __syncthreads();
    }
    if (tid == 0) bc[0] = red[0] / (float)NN;
    __syncthreads();
    const float mean = bc[0];

    // pass B: sum of squared deviations -> thr = mean + std(ddof=1)
    float ss = 0.f;
#pragma unroll
    for (int j = 0; j < NN / 256; ++j) {
        float v = md[tid + 256 * j] - mean;
        ss += v * v;
    }
    red[tid] = ss;
    __syncthreads();
    for (int off = 128; off > 0; off >>= 1) {
        if (tid < off) red[tid] += red[tid + off];
        __syncthreads();
    }
    if (tid == 0) bc[1] = mean + sqrtf(red[0] / (float)(NN - 1));

    // histogram of masked assignments
    for (int j = tid; j < KK; j += 256) hist[j] = 0;
    __syncthreads();
    const float thr = bc[1];
#pragma unroll
    for (int j = 0; j < NN / 256; ++j) {
        int i = tid + 256 * j;
        if (md[i] < thr) atomicAdd(&hist[nr[i]], 1);
    }
    __syncthreads();

    // asmk = counts*weights; L2-normalize the row
    float a[4];
    float sq = 0.f;
#pragma unroll
    for (int t = 0; t < 4; ++t) {
        int k = tid * 4 + t;
        a[t] = (float)hist[k] * weights[k];
        sq += a[t] * a[t];
    }
    red[tid] = sq;
    __syncthreads();
    for (int off = 128; off > 0; off >>= 1) {
        if (tid < off) red[tid] += red[tid + off];
        __syncthreads();
    }
    const float norm = sqrtf(red[0]);
    const float scale = 1.f / fmaxf(norm, 1e-12f);
#pragma unroll
    for (int t = 0; t < 4; ++t) {
        int k = tid * 4 + t;
        out[(size_t)b * KK + k] = a[t] * scale;
    }
}

extern "C" void kernel_launch(void* const* d_in, const int* in_sizes, int n_in,
                              void* d_out, int out_size, void* d_ws, size_t ws_size,
                              hipStream_t stream) {
    const float* x = (const float*)d_in[0];
    const float* cent = (const float*)d_in[1];
    const float* weights = (const float*)d_in[2];
    float* out = (float*)d_out;

    float* min_d = (float*)d_ws;
    int* nearest = (int*)((char*)d_ws + (size_t)NPTS * 4);
    float* cnorm = (float*)((char*)d_ws + (size_t)NPTS * 8);

    cnorm_kernel<<<KK / 256, 256, 0, stream>>>(cent, cnorm);
    assign_kernel<<<NPTS / 128, 256, 0, stream>>>(x, cent, cnorm, min_d, nearest);
    finalize_kernel<<<BB, 256, 0, stream>>>(min_d, nearest, weights, out);
}

// Round 3
// 124.777 us; speedup vs baseline: 4.7275x; 4.7275x over previous
//
#include <hip/hip_runtime.h>
#include <math.h>

#define BB 16
#define NN 4096
#define DD 128
#define KK 1024
#define NPTS (BB*NN)

typedef _Float16 half8 __attribute__((ext_vector_type(8)));
typedef float f32x16 __attribute__((ext_vector_type(16)));

static __device__ __forceinline__ uint pack2(float a, float b) {
    _Float16 ha = (_Float16)a, hb = (_Float16)b;
    unsigned short ua = __builtin_bit_cast(unsigned short, ha);
    unsigned short ub = __builtin_bit_cast(unsigned short, hb);
    return (uint)ua | ((uint)ub << 16);
}

// ---------------- kernel 0: centroid prep ----------------
// Per centroid row: fp16 split (hi + lo*1024) packed to u32 [1024][64], plus
// ||c||^2 in double -> cn (fp32).
__global__ void cprep_kernel(const float* __restrict__ cent,
                             uint* __restrict__ chig, uint* __restrict__ clog,
                             float* __restrict__ cn) {
    const int row = blockIdx.x * 4 + (threadIdx.x >> 6);
    const int lane = threadIdx.x & 63;
    float2 v = ((const float2*)(cent + (size_t)row * DD))[lane];
    _Float16 h0 = (_Float16)v.x, h1 = (_Float16)v.y;
    float r0 = (v.x - (float)h0) * 1024.f, r1 = (v.y - (float)h1) * 1024.f;
    chig[row * 64 + lane] = pack2(v.x, v.y);
    clog[row * 64 + lane] = pack2(r0, r1);
    double s = (double)v.x * v.x + (double)v.y * v.y;
#pragma unroll
    for (int m = 1; m < 64; m <<= 1) s += __shfl_xor(s, m);
    if (lane == 0) cn[row] = (float)s;
}

// ---------------- kernel 1: nearest-centroid via split-fp16 MFMA ----------------
// Block: 256 threads = 4 waves, block tile 128 points. Wave w owns points
// [w*32, w*32+32). Per wave: 32x32 output tile vs each of 32 N-tiles (32 cents).
// A (x) fragments persistent in VGPRs: x_hi + x_lo*1024 (fp16 split).
// B (c) tiles double-buffered in LDS (hi+lo), XOR-swizzled 16B slots.
// dot = hh + cross/1024 where cross = x_hi*c_lo_s + x_lo_s*c_hi  (lo_s = lo*1024).
// A-frag (32x16 f16): lane l -> m = l&31, k = (l>>5)*8 + i (8 contiguous k).
// B-frag (16x32 f16): lane l -> n = l&31, k = (l>>5)*8 + i  => read row n of c.
// D: col(n) = lane&31, row(m) = (r&3) + 8*(r>>2) + 4*(lane>>5)   [guide-verified]
__launch_bounds__(256, 2)
__global__ void assign_mfma(const float* __restrict__ x,
                            const uint* __restrict__ chig, const uint* __restrict__ clog,
                            const float* __restrict__ cn,
                            float* __restrict__ min_d, int* __restrict__ nearest) {
    __shared__ uint chi[2][2048];   // 32 rows x 64 u32 (128 f16), swizzled
    __shared__ uint clo[2][2048];
    __shared__ float cnS[KK];
    __shared__ float xnS[128];

    const int tid = threadIdx.x;
    const int lane = tid & 63;
    const int w = tid >> 6;
    const int l31 = lane & 31;
    const int lh = lane >> 5;

    // ---- prologue: issue c-tile-0 loads early ----
    uint4 rh[2], rl[2];
    const uint4* gh = (const uint4*)chig;
    const uint4* gl = (const uint4*)clog;
#pragma unroll
    for (int j = 0; j < 2; ++j) {
        rh[j] = gh[tid + 256 * j];
        rl[j] = gl[tid + 256 * j];
    }

    // A fragments from global + fp16 split; also per-row ||x||^2
    half8 ahi[8], alo[8];
    float xs = 0.f;
    const float4* xrow = (const float4*)(x + ((size_t)blockIdx.x * 128 + w * 32 + l31) * DD);
#pragma unroll
    for (int c = 0; c < 8; ++c) {
        float4 v0 = xrow[c * 4 + lh * 2];
        float4 v1 = xrow[c * 4 + lh * 2 + 1];
        float vv[8] = {v0.x, v0.y, v0.z, v0.w, v1.x, v1.y, v1.z, v1.w};
#pragma unroll
        for (int i = 0; i < 8; ++i) {
            _Float16 h = (_Float16)vv[i];
            ahi[c][i] = h;
            alo[c][i] = (_Float16)((vv[i] - (float)h) * 1024.f);
            xs = fmaf(vv[i], vv[i], xs);
        }
    }
    xs += __shfl_xor(xs, 32);           // other k-half of the same row
    if (lh == 0) xnS[w * 32 + l31] = xs;

#pragma unroll
    for (int j = 0; j < 4; ++j) cnS[tid + 256 * j] = cn[tid + 256 * j];

    // write c-tile 0 to LDS buf0 (swizzled)
#pragma unroll
    for (int j = 0; j < 2; ++j) {
        int i = tid + 256 * j;
        int row = i >> 4, slot = i & 15;
        int dst = row * 64 + ((slot ^ (row & 15)) << 2);
        *(uint4*)&chi[0][dst] = rh[j];
        *(uint4*)&clo[0][dst] = rl[j];
    }
    __syncthreads();

    float best[16];
    int bk[16];
#pragma unroll
    for (int r = 0; r < 16; ++r) { best[r] = INFINITY; bk[r] = 0; }

    for (int nt = 0; nt < 32; ++nt) {
        const int buf = nt & 1;
        if (nt < 31) {  // issue next tile's global loads early (hide under MFMA)
#pragma unroll
            for (int j = 0; j < 2; ++j) {
                rh[j] = gh[(nt + 1) * 512 + tid + 256 * j];
                rl[j] = gl[(nt + 1) * 512 + tid + 256 * j];
            }
        }
        f32x16 ahh, acr;
#pragma unroll
        for (int i = 0; i < 16; ++i) { ahh[i] = 0.f; acr[i] = 0.f; }
#pragma unroll
        for (int c = 0; c < 8; ++c) {
            int bidx = l31 * 64 + (((c * 2 + lh) ^ (l31 & 15)) << 2);
            half8 bh = *(const half8*)&chi[buf][bidx];
            half8 bl = *(const half8*)&clo[buf][bidx];
            ahh = __builtin_amdgcn_mfma_f32_32x32x16_f16(ahi[c], bh, ahh, 0, 0, 0);
            acr = __builtin_amdgcn_mfma_f32_32x32x16_f16(ahi[c], bl, acr, 0, 0, 0);
            acr = __builtin_amdgcn_mfma_f32_32x32x16_f16(alo[c], bh, acr, 0, 0, 0);
        }
        const int kcur = nt * 32 + l31;
        const float cnv = cnS[kcur];
#pragma unroll
        for (int r = 0; r < 16; ++r) {
            float v = cnv - 2.f * ahh[r] - 0.001953125f * acr[r];  // 2/1024 undoes lo scaling
            if (v < best[r]) { best[r] = v; bk[r] = kcur; }        // strict <: first-min
        }
        if (nt < 31) {  // write-late into the other buffer, then barrier
#pragma unroll
            for (int j = 0; j < 2; ++j) {
                int i = tid + 256 * j;
                int row = i >> 4, slot = i & 15;
                int dst = row * 64 + ((slot ^ (row & 15)) << 2);
                *(uint4*)&chi[buf ^ 1][dst] = rh[j];
                *(uint4*)&clo[buf ^ 1][dst] = rl[j];
            }
            __syncthreads();
        }
    }

    // cross-lane argmin over the 32 columns (xor masks < 32 stay in half-wave)
#pragma unroll
    for (int r = 0; r < 16; ++r) {
        float bv = best[r]; int bi = bk[r];
#pragma unroll
        for (int m = 1; m < 32; m <<= 1) {
            float ov = __shfl_xor(bv, m);
            int oi = __shfl_xor(bi, m);
            if (ov < bv || (ov == bv && oi < bi)) { bv = ov; bi = oi; }
        }
        best[r] = bv; bk[r] = bi;
    }

    if (l31 == 0) {
#pragma unroll
        for (int r = 0; r < 16; ++r) {
            int rowl = w * 32 + (r & 3) + 8 * (r >> 2) + 4 * lh;
            float sq = xnS[rowl] + best[r];
            int p = blockIdx.x * 128 + rowl;
            min_d[p] = sqrtf(fmaxf(sq, 0.f));
            nearest[p] = bk[r];
        }
    }
}

// ---------------- kernel 2: per-batch stats + histogram + normalize ----------------
__global__ void finalize_kernel(const float* __restrict__ min_d, const int* __restrict__ nearest,
                                const float* __restrict__ weights, float* __restrict__ out) {
    __shared__ float red[256];
    __shared__ int hist[KK];
    __shared__ float bc[2];  // mean, thr
    const int b = blockIdx.x;
    const int tid = threadIdx.x;
    const float* md = min_d + (size_t)b * NN;
    const int* nr = nearest + (size_t)b * NN;

    float s = 0.f;
#pragma unroll
    for (int j = 0; j < NN / 256; ++j) s += md[tid + 256 * j];
    red[tid] = s;
    __syncthreads();
    for (int off = 128; off > 0; off >>= 1) {
        if (tid < off) red[tid] += red[tid + off];
        __syncthreads();
    }
    if (tid == 0) bc[0] = red[0] / (float)NN;
    __syncthreads();
    const float mean = bc[0];

    float ss = 0.f;
#pragma unroll
    for (int j = 0; j < NN / 256; ++j) {
        float v = md[tid + 256 * j] - mean;
        ss += v * v;
    }
    red[tid] = ss;
    __syncthreads();
    for (int off = 128; off > 0; off >>= 1) {
        if (tid < off) red[tid] += red[tid + off];
        __syncthreads();
    }
    if (tid == 0) bc[1] = mean + sqrtf(red[0] / (float)(NN - 1));

    for (int j = tid; j < KK; j += 256) hist[j] = 0;
    __syncthreads();
    const float thr = bc[1];
#pragma unroll
    for (int j = 0; j < NN / 256; ++j) {
        int i = tid + 256 * j;
        if (md[i] < thr) atomicAdd(&hist[nr[i]], 1);
    }
    __syncthreads();

    float a[4];
    float sq = 0.f;
#pragma unroll
    for (int t = 0; t < 4; ++t) {
        int k = tid * 4 + t;
        a[t] = (float)hist[k] * weights[k];
        sq += a[t] * a[t];
    }
    red[tid] = sq;
    __syncthreads();
    for (int off = 128; off > 0; off >>= 1) {
        if (tid < off) red[tid] += red[tid + off];
        __syncthreads();
    }
    const float norm = sqrtf(red[0]);
    const float scale = 1.f / fmaxf(norm, 1e-12f);
#pragma unroll
    for (int t = 0; t < 4; ++t) {
        int k = tid * 4 + t;
        out[(size_t)b * KK + k] = a[t] * scale;
    }
}

extern "C" void kernel_launch(void* const* d_in, const int* in_sizes, int n_in,
                              void* d_out, int out_size, void* d_ws, size_t ws_size,
                              hipStream_t stream) {
    const float* x = (const float*)d_in[0];
    const float* cent = (const float*)d_in[1];
    const float* weights = (const float*)d_in[2];
    float* out = (float*)d_out;

    char* ws = (char*)d_ws;
    float* min_d   = (float*)(ws + 0);
    int*   nearest = (int*)  (ws + 262144);
    float* cn      = (float*)(ws + 524288);
    uint*  chig    = (uint*) (ws + 528384);
    uint*  clog    = (uint*) (ws + 790528);

    cprep_kernel<<<KK / 4, 256, 0, stream>>>(cent, chig, clog, cn);
    assign_mfma<<<NPTS / 128, 256, 0, stream>>>(x, chig, clog, cn, min_d, nearest);
    finalize_kernel<<<BB, 256, 0, stream>>>(min_d, nearest, weights, out);
}

// Round 4
// 96.082 us; speedup vs baseline: 6.1393x; 1.2986x over previous
//
#include <hip/hip_runtime.h>
#include <math.h>

#define BB 16
#define NN 4096
#define DD 128
#define KK 1024
#define NPTS (BB*NN)

typedef _Float16 half8 __attribute__((ext_vector_type(8)));
typedef float f32x16 __attribute__((ext_vector_type(16)));

static __device__ __forceinline__ uint pack2(float a, float b) {
    _Float16 ha = (_Float16)a, hb = (_Float16)b;
    unsigned short ua = __builtin_bit_cast(unsigned short, ha);
    unsigned short ub = __builtin_bit_cast(unsigned short, hb);
    return (uint)ua | ((uint)ub << 16);
}

// ---------------- kernel 0a: centroid squared norms (double accum) ----------------
__global__ void cnorm_kernel(const float* __restrict__ c, float* __restrict__ cnorm) {
    int k = blockIdx.x * 256 + threadIdx.x;
    if (k >= KK) return;
    const float* row = c + k * DD;
    double s = 0.0;
#pragma unroll
    for (int d = 0; d < DD; ++d) { double v = (double)row[d]; s += v * v; }
    cnorm[k] = (float)s;
}

// ---------------- kernel 0b: pre-permute centroids into per-lane B-fragment order ----------------
// Fragment (nt, c, lane) = cent row (nt*32 + (lane&31)), d in [c*16+(lane>>5)*8, +8),
// split into fp16 hi + (lo*1024), packed as uint4. This is exactly the
// mfma_f32_32x32x16_f16 B-operand layout verified on HW by round 3's pass.
__global__ void cfrag_kernel(const float* __restrict__ cent,
                             uint4* __restrict__ cfh, uint4* __restrict__ cfl) {
    const int gid = blockIdx.x * 256 + threadIdx.x;   // [0, 32*8*64)
    const int nt = gid >> 9;
    const int c = (gid >> 6) & 7;
    const int lane = gid & 63;
    const int row = nt * 32 + (lane & 31);
    const int d0 = c * 16 + (lane >> 5) * 8;
    const float* src = cent + (size_t)row * DD + d0;
    float v[8];
#pragma unroll
    for (int i = 0; i < 8; ++i) v[i] = src[i];
    float lo[8];
#pragma unroll
    for (int i = 0; i < 8; ++i) {
        _Float16 h = (_Float16)v[i];
        lo[i] = (v[i] - (float)h) * 1024.f;
    }
    uint4 h4, l4;
    h4.x = pack2(v[0], v[1]); h4.y = pack2(v[2], v[3]);
    h4.z = pack2(v[4], v[5]); h4.w = pack2(v[6], v[7]);
    l4.x = pack2(lo[0], lo[1]); l4.y = pack2(lo[2], lo[3]);
    l4.z = pack2(lo[4], lo[5]); l4.w = pack2(lo[6], lo[7]);
    cfh[gid] = h4;
    cfl[gid] = l4;
}

// ---------------- kernel 1: nearest-centroid, single-wave blocks, no LDS, no barriers ----------------
// 2048 blocks x 64 threads; each wave owns 32 points (A-frags persistent in VGPRs)
// and scans all 32 centroid tiles. B-fragments stream global->reg with rolling
// prefetch (slot c reloaded for tile nt+1 right after its last use in tile nt)
// -> counted vmcnt, no drains, fully independent waves.
__launch_bounds__(64, 2)
__global__ void assign_mfma2(const float* __restrict__ x,
                             const uint4* __restrict__ cfh, const uint4* __restrict__ cfl,
                             const float* __restrict__ cn,
                             float* __restrict__ min_d, int* __restrict__ nearest) {
    const int lane = threadIdx.x;
    const int l31 = lane & 31;
    const int lh = lane >> 5;
    const int p0 = blockIdx.x * 32;

    // A fragments (x rows) + per-row ||x||^2 (same construction as R3, HW-verified)
    half8 ahi[8], alo[8];
    float xs = 0.f;
    const float4* xrow = (const float4*)(x + (size_t)(p0 + l31) * DD);
#pragma unroll
    for (int c = 0; c < 8; ++c) {
        float4 v0 = xrow[c * 4 + lh * 2];
        float4 v1 = xrow[c * 4 + lh * 2 + 1];
        float vv[8] = {v0.x, v0.y, v0.z, v0.w, v1.x, v1.y, v1.z, v1.w};
#pragma unroll
        for (int i = 0; i < 8; ++i) {
            _Float16 h = (_Float16)vv[i];
            ahi[c][i] = h;
            alo[c][i] = (_Float16)((vv[i] - (float)h) * 1024.f);
            xs = fmaf(vv[i], vv[i], xs);
        }
    }
    xs += __shfl_xor(xs, 32);   // merge the two d-halves: lane l now has ||row l31||^2

    // prologue: prefetch tile 0's B fragments
    uint4 bh[8], bl[8];
#pragma unroll
    for (int c = 0; c < 8; ++c) {
        bh[c] = cfh[c * 64 + lane];
        bl[c] = cfl[c * 64 + lane];
    }

    float best[16];
    int bk[16];
#pragma unroll
    for (int r = 0; r < 16; ++r) { best[r] = INFINITY; bk[r] = 0; }

    for (int nt = 0; nt < 32; ++nt) {
        const float cnv = cn[nt * 32 + l31];    // issued early, used in epilogue
        const int ntn = (nt + 1) & 31;          // branchless wrap (tile 0 reload unused)
        f32x16 hh, cr0, cr1;
#pragma unroll
        for (int i = 0; i < 16; ++i) { hh[i] = 0.f; cr0[i] = 0.f; cr1[i] = 0.f; }
#pragma unroll
        for (int c = 0; c < 8; ++c) {
            half8 vbh = __builtin_bit_cast(half8, bh[c]);
            half8 vbl = __builtin_bit_cast(half8, bl[c]);
            hh  = __builtin_amdgcn_mfma_f32_32x32x16_f16(ahi[c], vbh, hh, 0, 0, 0);
            cr0 = __builtin_amdgcn_mfma_f32_32x32x16_f16(ahi[c], vbl, cr0, 0, 0, 0);
            cr1 = __builtin_amdgcn_mfma_f32_32x32x16_f16(alo[c], vbh, cr1, 0, 0, 0);
            // rolling prefetch: slot c is dead for this tile now -> load next tile's
            bh[c] = cfh[(size_t)(ntn * 8 + c) * 64 + lane];
            bl[c] = cfl[(size_t)(ntn * 8 + c) * 64 + lane];
        }
        const int kcur = nt * 32 + l31;
#pragma unroll
        for (int r = 0; r < 16; ++r) {
            float v = cnv - 2.f * hh[r] - 0.001953125f * (cr0[r] + cr1[r]);
            if (v < best[r]) { best[r] = v; bk[r] = kcur; }   // strict <: first-min, k ascending
        }
    }

    // cross-lane argmin over the 32 centroid columns (masks < 32 stay in half-wave)
#pragma unroll
    for (int r = 0; r < 16; ++r) {
        float bv = best[r]; int bi = bk[r];
#pragma unroll
        for (int m = 1; m < 32; m <<= 1) {
            float ov = __shfl_xor(bv, m);
            int oi = __shfl_xor(bi, m);
            if (ov < bv || (ov == bv && oi < bi)) { bv = ov; bi = oi; }
        }
        best[r] = bv; bk[r] = bi;
    }

    // gather ||x||^2 for this half's output rows (static shfl indices, all lanes)
    float xnv[16];
#pragma unroll
    for (int r = 0; r < 16; ++r)
        xnv[r] = __shfl(xs, (r & 3) + 8 * (r >> 2) + 4 * lh);

    if (l31 == 0) {
#pragma unroll
        for (int r = 0; r < 16; ++r) {
            int m = (r & 3) + 8 * (r >> 2) + 4 * lh;   // D-layout row (HW-verified in R3)
            float sq = xnv[r] + best[r];
            min_d[p0 + m] = sqrtf(fmaxf(sq, 0.f));
            nearest[p0 + m] = bk[r];
        }
    }
}

// ---------------- kernel 2: per-batch stats + histogram + normalize ----------------
__global__ void finalize_kernel(const float* __restrict__ min_d, const int* __restrict__ nearest,
                                const float* __restrict__ weights, float* __restrict__ out) {
    __shared__ float red[256];
    __shared__ int hist[KK];
    __shared__ float bc[2];  // mean, thr
    const int b = blockIdx.x;
    const int tid = threadIdx.x;
    const float* md = min_d + (size_t)b * NN;
    const int* nr = nearest + (size_t)b * NN;

    float s = 0.f;
#pragma unroll
    for (int j = 0; j < NN / 256; ++j) s += md[tid + 256 * j];
    red[tid] = s;
    __syncthreads();
    for (int off = 128; off > 0; off >>= 1) {
        if (tid < off) red[tid] += red[tid + off];
        __syncthreads();
    }
    if (tid == 0) bc[0] = red[0] / (float)NN;
    __syncthreads();
    const float mean = bc[0];

    float ss = 0.f;
#pragma unroll
    for (int j = 0; j < NN / 256; ++j) {
        float v = md[tid + 256 * j] - mean;
        ss += v * v;
    }
    red[tid] = ss;
    __syncthreads();
    for (int off = 128; off > 0; off >>= 1) {
        if (tid < off) red[tid] += red[tid + off];
        __syncthreads();
    }
    if (tid == 0) bc[1] = mean + sqrtf(red[0] / (float)(NN - 1));

    for (int j = tid; j < KK; j += 256) hist[j] = 0;
    __syncthreads();
    const float thr = bc[1];
#pragma unroll
    for (int j = 0; j < NN / 256; ++j) {
        int i = tid + 256 * j;
        if (md[i] < thr) atomicAdd(&hist[nr[i]], 1);
    }
    __syncthreads();

    float a[4];
    float sq = 0.f;
#pragma unroll
    for (int t = 0; t < 4; ++t) {
        int k = tid * 4 + t;
        a[t] = (float)hist[k] * weights[k];
        sq += a[t] * a[t];
    }
    red[tid] = sq;
    __syncthreads();
    for (int off = 128; off > 0; off >>= 1) {
        if (tid < off) red[tid] += red[tid + off];
        __syncthreads();
    }
    const float norm = sqrtf(red[0]);
    const float scale = 1.f / fmaxf(norm, 1e-12f);
#pragma unroll
    for (int t = 0; t < 4; ++t) {
        int k = tid * 4 + t;
        out[(size_t)b * KK + k] = a[t] * scale;
    }
}

extern "C" void kernel_launch(void* const* d_in, const int* in_sizes, int n_in,
                              void* d_out, int out_size, void* d_ws, size_t ws_size,
                              hipStream_t stream) {
    const float* x = (const float*)d_in[0];
    const float* cent = (const float*)d_in[1];
    const float* weights = (const float*)d_in[2];
    float* out = (float*)d_out;

    char* ws = (char*)d_ws;
    float* min_d   = (float*)(ws + 0);
    int*   nearest = (int*)  (ws + 262144);
    float* cn      = (float*)(ws + 524288);
    uint4* cfh     = (uint4*)(ws + 528384);
    uint4* cfl     = (uint4*)(ws + 790528);

    cnorm_kernel<<<KK / 256, 256, 0, stream>>>(cent, cn);
    cfrag_kernel<<<64, 256, 0, stream>>>(cent, cfh, cfl);
    assign_mfma2<<<NPTS / 32, 64, 0, stream>>>(x, cfh, cfl, cn, min_d, nearest);
    finalize_kernel<<<BB, 256, 0, stream>>>(min_d, nearest, weights, out);
}

// Round 5
// 87.243 us; speedup vs baseline: 6.7613x; 1.1013x over previous
//
#include <hip/hip_runtime.h>
#include <math.h>

#define BB 16
#define NN 4096
#define DD 128
#define KK 1024
#define NPTS (BB*NN)

typedef _Float16 half8 __attribute__((ext_vector_type(8)));
typedef float f32x16 __attribute__((ext_vector_type(16)));

static __device__ __forceinline__ uint pack2(float a, float b) {
    _Float16 ha = (_Float16)a, hb = (_Float16)b;
    unsigned short ua = __builtin_bit_cast(unsigned short, ha);
    unsigned short ub = __builtin_bit_cast(unsigned short, hb);
    return (uint)ua | ((uint)ub << 16);
}

// ---------------- kernel 0a: centroid squared norms (double accum) ----------------
__global__ void cnorm_kernel(const float* __restrict__ c, float* __restrict__ cnorm) {
    int k = blockIdx.x * 256 + threadIdx.x;
    if (k >= KK) return;
    const float* row = c + k * DD;
    double s = 0.0;
#pragma unroll
    for (int d = 0; d < DD; ++d) { double v = (double)row[d]; s += v * v; }
    cnorm[k] = (float)s;
}

// ---------------- kernel 0b: pre-permute centroids into per-lane B-fragment order ----------------
// Fragment (nt, c, lane) = cent row (nt*32 + (lane&31)), d in [c*16+(lane>>5)*8, +8),
// split into fp16 hi + (lo*1024), packed as uint4 (HW-verified layout, R3/R4 pass).
__global__ void cfrag_kernel(const float* __restrict__ cent,
                             uint4* __restrict__ cfh, uint4* __restrict__ cfl) {
    const int gid = blockIdx.x * 256 + threadIdx.x;   // [0, 32*8*64)
    const int nt = gid >> 9;
    const int c = (gid >> 6) & 7;
    const int lane = gid & 63;
    const int row = nt * 32 + (lane & 31);
    const int d0 = c * 16 + (lane >> 5) * 8;
    const float* src = cent + (size_t)row * DD + d0;
    float v[8];
#pragma unroll
    for (int i = 0; i < 8; ++i) v[i] = src[i];
    float lo[8];
#pragma unroll
    for (int i = 0; i < 8; ++i) {
        _Float16 h = (_Float16)v[i];
        lo[i] = (v[i] - (float)h) * 1024.f;
    }
    uint4 h4, l4;
    h4.x = pack2(v[0], v[1]); h4.y = pack2(v[2], v[3]);
    h4.z = pack2(v[4], v[5]); h4.w = pack2(v[6], v[7]);
    l4.x = pack2(lo[0], lo[1]); l4.y = pack2(lo[2], lo[3]);
    l4.z = pack2(lo[4], lo[5]); l4.w = pack2(lo[6], lo[7]);
    cfh[gid] = h4;
    cfl[gid] = l4;
}

// ---------------- kernel 1: nearest-centroid, single-wave blocks, reg ping-pong ----------------
// 2048 blocks x 64 threads; wave owns 32 points (A-frags persistent in VGPRs).
// B-fragments stream global->reg in HALF-TILE ping-pong buffers (h0/l0, h1/l1).
// sched_barrier(0) after each load cluster forbids the scheduler from sinking
// loads to their uses (R4 failure mode: regalloc collapsed the prefetch,
// VGPR=92, every load stalled ~200cy). Loads stay >=1 half-tile (~300cy incl.
// epilogue) ahead of use; compiler-tracked vmcnt waits are then near-free.
__launch_bounds__(64, 2)
__global__ void assign_mfma2(const float* __restrict__ x,
                             const uint4* __restrict__ cfh, const uint4* __restrict__ cfl,
                             const float* __restrict__ cn,
                             float* __restrict__ min_d, int* __restrict__ nearest) {
    const int lane = threadIdx.x;
    const int l31 = lane & 31;
    const int lh = lane >> 5;
    const int p0 = blockIdx.x * 32;

    // A fragments (x rows) + per-row ||x||^2 (identical to R3/R4, HW-verified)
    half8 ahi[8], alo[8];
    float xs = 0.f;
    const float4* xrow = (const float4*)(x + (size_t)(p0 + l31) * DD);
#pragma unroll
    for (int c = 0; c < 8; ++c) {
        float4 v0 = xrow[c * 4 + lh * 2];
        float4 v1 = xrow[c * 4 + lh * 2 + 1];
        float vv[8] = {v0.x, v0.y, v0.z, v0.w, v1.x, v1.y, v1.z, v1.w};
#pragma unroll
        for (int i = 0; i < 8; ++i) {
            _Float16 h = (_Float16)vv[i];
            ahi[c][i] = h;
            alo[c][i] = (_Float16)((vv[i] - (float)h) * 1024.f);
            xs = fmaf(vv[i], vv[i], xs);
        }
    }
    xs += __shfl_xor(xs, 32);   // merge the two d-halves: lane l has ||row l31||^2

    // ping-pong half-tile buffers (4 slots each)
    uint4 h0[4], l0[4], h1[4], l1[4];
#pragma unroll
    for (int c = 0; c < 4; ++c) {             // prologue: half0 of tile 0
        h0[c] = cfh[c * 64 + lane];
        l0[c] = cfl[c * 64 + lane];
    }

    float best[16];
    int bk[16];
#pragma unroll
    for (int r = 0; r < 16; ++r) { best[r] = INFINITY; bk[r] = 0; }

    for (int nt = 0; nt < 32; ++nt) {
        const int ntn = (nt + 1) & 31;          // branchless wrap (last reload unused)
        const float cnv = cn[nt * 32 + l31];    // issued here, used in epilogue
        f32x16 hh, cr0, cr1;
#pragma unroll
        for (int i = 0; i < 16; ++i) { hh[i] = 0.f; cr0[i] = 0.f; cr1[i] = 0.f; }

        // prefetch half1 of tile nt
#pragma unroll
        for (int c = 0; c < 4; ++c) {
            h1[c] = cfh[((size_t)nt * 8 + 4 + c) * 64 + lane];
            l1[c] = cfl[((size_t)nt * 8 + 4 + c) * 64 + lane];
        }
        __builtin_amdgcn_sched_barrier(0);   // loads above, MFMAs below

        // compute half0 (c = 0..3) — accumulator order identical to R4
#pragma unroll
        for (int c = 0; c < 4; ++c) {
            half8 vbh = __builtin_bit_cast(half8, h0[c]);
            half8 vbl = __builtin_bit_cast(half8, l0[c]);
            hh  = __builtin_amdgcn_mfma_f32_32x32x16_f16(ahi[c], vbh, hh, 0, 0, 0);
            cr0 = __builtin_amdgcn_mfma_f32_32x32x16_f16(ahi[c], vbl, cr0, 0, 0, 0);
            cr1 = __builtin_amdgcn_mfma_f32_32x32x16_f16(alo[c], vbh, cr1, 0, 0, 0);
        }

        // prefetch half0 of tile nt+1
#pragma unroll
        for (int c = 0; c < 4; ++c) {
            h0[c] = cfh[((size_t)ntn * 8 + c) * 64 + lane];
            l0[c] = cfl[((size_t)ntn * 8 + c) * 64 + lane];
        }
        __builtin_amdgcn_sched_barrier(0);   // loads above, MFMAs below

        // compute half1 (c = 4..7)
#pragma unroll
        for (int c = 0; c < 4; ++c) {
            half8 vbh = __builtin_bit_cast(half8, h1[c]);
            half8 vbl = __builtin_bit_cast(half8, l1[c]);
            hh  = __builtin_amdgcn_mfma_f32_32x32x16_f16(ahi[4 + c], vbh, hh, 0, 0, 0);
            cr0 = __builtin_amdgcn_mfma_f32_32x32x16_f16(ahi[4 + c], vbl, cr0, 0, 0, 0);
            cr1 = __builtin_amdgcn_mfma_f32_32x32x16_f16(alo[4 + c], vbh, cr1, 0, 0, 0);
        }

        const int kcur = nt * 32 + l31;
#pragma unroll
        for (int r = 0; r < 16; ++r) {
            float v = cnv - 2.f * hh[r] - 0.001953125f * (cr0[r] + cr1[r]);
            if (v < best[r]) { best[r] = v; bk[r] = kcur; }   // strict <: first-min, k ascending
        }
    }

    // cross-lane argmin over the 32 centroid columns (masks < 32 stay in half-wave)
#pragma unroll
    for (int r = 0; r < 16; ++r) {
        float bv = best[r]; int bi = bk[r];
#pragma unroll
        for (int m = 1; m < 32; m <<= 1) {
            float ov = __shfl_xor(bv, m);
            int oi = __shfl_xor(bi, m);
            if (ov < bv || (ov == bv && oi < bi)) { bv = ov; bi = oi; }
        }
        best[r] = bv; bk[r] = bi;
    }

    // gather ||x||^2 for this half's output rows (static shfl indices, all lanes)
    float xnv[16];
#pragma unroll
    for (int r = 0; r < 16; ++r)
        xnv[r] = __shfl(xs, (r & 3) + 8 * (r >> 2) + 4 * lh);

    if (l31 == 0) {
#pragma unroll
        for (int r = 0; r < 16; ++r) {
            int m = (r & 3) + 8 * (r >> 2) + 4 * lh;   // D-layout row (HW-verified)
            float sq = xnv[r] + best[r];
            min_d[p0 + m] = sqrtf(fmaxf(sq, 0.f));
            nearest[p0 + m] = bk[r];
        }
    }
}

// ---------------- kernel 2: per-batch stats + histogram + normalize ----------------
__global__ void finalize_kernel(const float* __restrict__ min_d, const int* __restrict__ nearest,
                                const float* __restrict__ weights, float* __restrict__ out) {
    __shared__ float red[256];
    __shared__ int hist[KK];
    __shared__ float bc[2];  // mean, thr
    const int b = blockIdx.x;
    const int tid = threadIdx.x;
    const float* md = min_d + (size_t)b * NN;
    const int* nr = nearest + (size_t)b * NN;

    float s = 0.f;
#pragma unroll
    for (int j = 0; j < NN / 256; ++j) s += md[tid + 256 * j];
    red[tid] = s;
    __syncthreads();
    for (int off = 128; off > 0; off >>= 1) {
        if (tid < off) red[tid] += red[tid + off];
        __syncthreads();
    }
    if (tid == 0) bc[0] = red[0] / (float)NN;
    __syncthreads();
    const float mean = bc[0];

    float ss = 0.f;
#pragma unroll
    for (int j = 0; j < NN / 256; ++j) {
        float v = md[tid + 256 * j] - mean;
        ss += v * v;
    }
    red[tid] = ss;
    __syncthreads();
    for (int off = 128; off > 0; off >>= 1) {
        if (tid < off) red[tid] += red[tid + off];
        __syncthreads();
    }
    if (tid == 0) bc[1] = mean + sqrtf(red[0] / (float)(NN - 1));

    for (int j = tid; j < KK; j += 256) hist[j] = 0;
    __syncthreads();
    const float thr = bc[1];
#pragma unroll
    for (int j = 0; j < NN / 256; ++j) {
        int i = tid + 256 * j;
        if (md[i] < thr) atomicAdd(&hist[nr[i]], 1);
    }
    __syncthreads();

    float a[4];
    float sq = 0.f;
#pragma unroll
    for (int t = 0; t < 4; ++t) {
        int k = tid * 4 + t;
        a[t] = (float)hist[k] * weights[k];
        sq += a[t] * a[t];
    }
    red[tid] = sq;
    __syncthreads();
    for (int off = 128; off > 0; off >>= 1) {
        if (tid < off) red[tid] += red[tid + off];
        __syncthreads();
    }
    const float norm = sqrtf(red[0]);
    const float scale = 1.f / fmaxf(norm, 1e-12f);
#pragma unroll
    for (int t = 0; t < 4; ++t) {
        int k = tid * 4 + t;
        out[(size_t)b * KK + k] = a[t] * scale;
    }
}

extern "C" void kernel_launch(void* const* d_in, const int* in_sizes, int n_in,
                              void* d_out, int out_size, void* d_ws, size_t ws_size,
                              hipStream_t stream) {
    const float* x = (const float*)d_in[0];
    const float* cent = (const float*)d_in[1];
    const float* weights = (const float*)d_in[2];
    float* out = (float*)d_out;

    char* ws = (char*)d_ws;
    float* min_d   = (float*)(ws + 0);
    int*   nearest = (int*)  (ws + 262144);
    float* cn      = (float*)(ws + 524288);
    uint4* cfh     = (uint4*)(ws + 528384);
    uint4* cfl     = (uint4*)(ws + 790528);

    cnorm_kernel<<<KK / 256, 256, 0, stream>>>(cent, cn);
    cfrag_kernel<<<64, 256, 0, stream>>>(cent, cfh, cfl);
    assign_mfma2<<<NPTS / 32, 64, 0, stream>>>(x, cfh, cfl, cn, min_d, nearest);
    finalize_kernel<<<BB, 256, 0, stream>>>(min_d, nearest, weights, out);
}

// Round 6
// 82.240 us; speedup vs baseline: 7.1727x; 1.0608x over previous
//
#include <hip/hip_runtime.h>
#include <math.h>

#define BB 16
#define NN 4096
#define DD 128
#define KK 1024
#define NPTS (BB*NN)

typedef _Float16 half8 __attribute__((ext_vector_type(8)));
typedef float f32x16 __attribute__((ext_vector_type(16)));

static __device__ __forceinline__ uint pack2(float a, float b) {
    _Float16 ha = (_Float16)a, hb = (_Float16)b;
    unsigned short ua = __builtin_bit_cast(unsigned short, ha);
    unsigned short ub = __builtin_bit_cast(unsigned short, hb);
    return (uint)ua | ((uint)ub << 16);
}

typedef __attribute__((address_space(1))) const void as1_void;
typedef __attribute__((address_space(3))) void as3_void;
static __device__ __forceinline__ void gld16(const void* g, void* l) {
    // async global->LDS, 16B/lane; LDS dest = uniform base + lane*16 (HW rule)
    __builtin_amdgcn_global_load_lds((as1_void*)g, (as3_void*)l, 16, 0, 0);
}

// ---------------- kernel 0a: centroid squared norms (wave per row, double shfl reduce) ----------------
__global__ void cnorm_kernel(const float* __restrict__ c, float* __restrict__ cnorm) {
    const int w = threadIdx.x >> 6, lane = threadIdx.x & 63;
    const int row = blockIdx.x * 4 + w;
    float2 v = ((const float2*)(c + (size_t)row * DD))[lane];
    double s = (double)v.x * v.x + (double)v.y * v.y;
#pragma unroll
    for (int m = 1; m < 64; m <<= 1) s += __shfl_xor(s, m);
    if (lane == 0) cnorm[row] = (float)s;
}

// ---------------- kernel 0b: pre-permute centroids into per-lane B-fragment order ----------------
// Fragment (nt, c, lane) = cent row (nt*32 + (lane&31)), d in [c*16+(lane>>5)*8, +8),
// split into fp16 hi + (lo*1024), packed as uint4 (HW-verified layout, R3-R5 pass).
__global__ void cfrag_kernel(const float* __restrict__ cent,
                             uint4* __restrict__ cfh, uint4* __restrict__ cfl) {
    const int gid = blockIdx.x * 256 + threadIdx.x;   // [0, 32*8*64)
    const int nt = gid >> 9;
    const int c = (gid >> 6) & 7;
    const int lane = gid & 63;
    const int row = nt * 32 + (lane & 31);
    const int d0 = c * 16 + (lane >> 5) * 8;
    const float* src = cent + (size_t)row * DD + d0;
    float v[8];
#pragma unroll
    for (int i = 0; i < 8; ++i) v[i] = src[i];
    float lo[8];
#pragma unroll
    for (int i = 0; i < 8; ++i) {
        _Float16 h = (_Float16)v[i];
        lo[i] = (v[i] - (float)h) * 1024.f;
    }
    uint4 h4, l4;
    h4.x = pack2(v[0], v[1]); h4.y = pack2(v[2], v[3]);
    h4.z = pack2(v[4], v[5]); h4.w = pack2(v[6], v[7]);
    l4.x = pack2(lo[0], lo[1]); l4.y = pack2(lo[2], lo[3]);
    l4.z = pack2(lo[4], lo[5]); l4.w = pack2(lo[6], lo[7]);
    cfh[gid] = h4;
    cfl[gid] = l4;
}

// ---------------- kernel 1: nearest-centroid, 4-wave blocks, LDS 2-phase double buffer ----------------
// 512 blocks x 256 threads; wave w owns points [block*128 + w*32, +32), A-frags in VGPRs.
// B fragments staged to LDS once per block via global_load_lds (16B/lane): layout is
// linear-in-lane by construction (pre-permuted cfh/cfl), so the uniform-base+lane*16
// rule holds and ds_read_b128 (lane -> base + lane*16) is conflict-free.
// 2-phase: stage tile nt+1 into buf^1, compute tile nt from buf, one barrier/tile.
// Staging is issued ~1500cy before the barrier drain -> drain is free.
__launch_bounds__(256, 2)
__global__ void assign_mfma3(const float* __restrict__ x,
                             const uint4* __restrict__ cfh, const uint4* __restrict__ cfl,
                             const float* __restrict__ cn,
                             float* __restrict__ min_d, int* __restrict__ nearest) {
    __shared__ uint4 Bh[2][8][64];   // [dbuf][frag][lane]
    __shared__ uint4 Bl[2][8][64];

    const int tid = threadIdx.x;
    const int lane = tid & 63;
    const int w = tid >> 6;
    const int l31 = lane & 31;
    const int lh = lane >> 5;
    const int p0 = blockIdx.x * 128 + w * 32;

    // prologue: stage tile 0 into buffer 0 (each wave stages 4 of 16 fragment-rows)
#pragma unroll
    for (int j = 0; j < 4; ++j) {
        const int idx = w + 4 * j;   // wave-uniform
        if (idx < 8) gld16(cfh + (size_t)idx * 64 + lane, &Bh[0][idx][0]);
        else         gld16(cfl + (size_t)(idx - 8) * 64 + lane, &Bl[0][idx - 8][0]);
    }

    // A fragments (x rows) + per-row ||x||^2 (identical numerics to R3-R5)
    half8 ahi[8], alo[8];
    float xs = 0.f;
    const float4* xrow = (const float4*)(x + (size_t)(p0 + l31) * DD);
#pragma unroll
    for (int c = 0; c < 8; ++c) {
        float4 v0 = xrow[c * 4 + lh * 2];
        float4 v1 = xrow[c * 4 + lh * 2 + 1];
        float vv[8] = {v0.x, v0.y, v0.z, v0.w, v1.x, v1.y, v1.z, v1.w};
#pragma unroll
        for (int i = 0; i < 8; ++i) {
            _Float16 h = (_Float16)vv[i];
            ahi[c][i] = h;
            alo[c][i] = (_Float16)((vv[i] - (float)h) * 1024.f);
            xs = fmaf(vv[i], vv[i], xs);
        }
    }
    xs += __shfl_xor(xs, 32);   // lane l now has ||row l31||^2

    float best[16];
    int bk[16];
#pragma unroll
    for (int r = 0; r < 16; ++r) { best[r] = INFINITY; bk[r] = 0; }

    __syncthreads();   // tile 0 staged (implicit vmcnt(0)+lgkmcnt(0) drain)

    int buf = 0;
    for (int nt = 0; nt < 32; ++nt) {
        // stage tile nt+1 into the other buffer (issued before compute -> latency hidden)
        if (nt < 31) {
            const int ntn = nt + 1;
#pragma unroll
            for (int j = 0; j < 4; ++j) {
                const int idx = w + 4 * j;
                if (idx < 8) gld16(cfh + ((size_t)ntn * 8 + idx) * 64 + lane, &Bh[buf ^ 1][idx][0]);
                else         gld16(cfl + ((size_t)ntn * 8 + idx - 8) * 64 + lane, &Bl[buf ^ 1][idx - 8][0]);
            }
        }

        const float cnv = cn[nt * 32 + l31];
        f32x16 hh, cr0, cr1;
#pragma unroll
        for (int i = 0; i < 16; ++i) { hh[i] = 0.f; cr0[i] = 0.f; cr1[i] = 0.f; }

#pragma unroll
        for (int c = 0; c < 8; ++c) {
            half8 vbh = __builtin_bit_cast(half8, Bh[buf][c][lane]);
            half8 vbl = __builtin_bit_cast(half8, Bl[buf][c][lane]);
            hh  = __builtin_amdgcn_mfma_f32_32x32x16_f16(ahi[c], vbh, hh, 0, 0, 0);
            cr0 = __builtin_amdgcn_mfma_f32_32x32x16_f16(ahi[c], vbl, cr0, 0, 0, 0);
            cr1 = __builtin_amdgcn_mfma_f32_32x32x16_f16(alo[c], vbh, cr1, 0, 0, 0);
        }

        const int kcur = nt * 32 + l31;
#pragma unroll
        for (int r = 0; r < 16; ++r) {
            float v = cnv - 2.f * hh[r] - 0.001953125f * (cr0[r] + cr1[r]);
            if (v < best[r]) { best[r] = v; bk[r] = kcur; }   // strict <: first-min, k ascending
        }

        if (nt < 31) __syncthreads();   // staging done + everyone finished reading buf
        buf ^= 1;
    }

    // cross-lane argmin over the 32 centroid columns (masks < 32 stay in half-wave)
#pragma unroll
    for (int r = 0; r < 16; ++r) {
        float bv = best[r]; int bi = bk[r];
#pragma unroll
        for (int m = 1; m < 32; m <<= 1) {
            float ov = __shfl_xor(bv, m);
            int oi = __shfl_xor(bi, m);
            if (ov < bv || (ov == bv && oi < bi)) { bv = ov; bi = oi; }
        }
        best[r] = bv; bk[r] = bi;
    }

    // gather ||x||^2 for this half's output rows (static shfl indices, all lanes)
    float xnv[16];
#pragma unroll
    for (int r = 0; r < 16; ++r)
        xnv[r] = __shfl(xs, (r & 3) + 8 * (r >> 2) + 4 * lh);

    if (l31 == 0) {
#pragma unroll
        for (int r = 0; r < 16; ++r) {
            int m = (r & 3) + 8 * (r >> 2) + 4 * lh;   // D-layout row (HW-verified)
            float sq = xnv[r] + best[r];
            min_d[p0 + m] = sqrtf(fmaxf(sq, 0.f));
            nearest[p0 + m] = bk[r];
        }
    }
}

// ---------------- kernel 2: per-batch stats + histogram + normalize (1024 threads) ----------------
__global__ void finalize_kernel(const float* __restrict__ min_d, const int* __restrict__ nearest,
                                const float* __restrict__ weights, float* __restrict__ out) {
    __shared__ float red[1024];
    __shared__ int hist[KK];
    __shared__ float bc[2];  // mean, thr
    const int b = blockIdx.x;
    const int tid = threadIdx.x;
    const float* md = min_d + (size_t)b * NN;
    const int* nr = nearest + (size_t)b * NN;

    // pass A: mean (two-pass std to match numpy numerics)
    float s = 0.f;
#pragma unroll
    for (int j = 0; j < NN / 1024; ++j) s += md[tid + 1024 * j];
    red[tid] = s;
    __syncthreads();
    for (int off = 512; off > 0; off >>= 1) {
        if (tid < off) red[tid] += red[tid + off];
        __syncthreads();
    }
    if (tid == 0) bc[0] = red[0] / (float)NN;
    __syncthreads();
    const float mean = bc[0];

    // pass B: sum of squared deviations -> thr = mean + std(ddof=1)
    float ss = 0.f;
#pragma unroll
    for (int j = 0; j < NN / 1024; ++j) {
        float v = md[tid + 1024 * j] - mean;
        ss += v * v;
    }
    red[tid] = ss;
    __syncthreads();
    for (int off = 512; off > 0; off >>= 1) {
        if (tid < off) red[tid] += red[tid + off];
        __syncthreads();
    }
    if (tid == 0) bc[1] = mean + sqrtf(red[0] / (float)(NN - 1));

    // histogram of masked assignments
    hist[tid] = 0;
    __syncthreads();
    const float thr = bc[1];
#pragma unroll
    for (int j = 0; j < NN / 1024; ++j) {
        int i = tid + 1024 * j;
        if (md[i] < thr) atomicAdd(&hist[nr[i]], 1);
    }
    __syncthreads();

    // asmk = counts*weights; L2-normalize the row (one k per thread)
    const float a = (float)hist[tid] * weights[tid];
    red[tid] = a * a;
    __syncthreads();
    for (int off = 512; off > 0; off >>= 1) {
        if (tid < off) red[tid] += red[tid + off];
        __syncthreads();
    }
    const float norm = sqrtf(red[0]);
    const float scale = 1.f / fmaxf(norm, 1e-12f);
    out[(size_t)b * KK + tid] = a * scale;
}

extern "C" void kernel_launch(void* const* d_in, const int* in_sizes, int n_in,
                              void* d_out, int out_size, void* d_ws, size_t ws_size,
                              hipStream_t stream) {
    const float* x = (const float*)d_in[0];
    const float* cent = (const float*)d_in[1];
    const float* weights = (const float*)d_in[2];
    float* out = (float*)d_out;

    char* ws = (char*)d_ws;
    float* min_d   = (float*)(ws + 0);
    int*   nearest = (int*)  (ws + 262144);
    float* cn      = (float*)(ws + 524288);
    uint4* cfh     = (uint4*)(ws + 528384);
    uint4* cfl     = (uint4*)(ws + 790528);

    cnorm_kernel<<<KK / 4, 256, 0, stream>>>(cent, cn);
    cfrag_kernel<<<64, 256, 0, stream>>>(cent, cfh, cfl);
    assign_mfma3<<<NPTS / 128, 256, 0, stream>>>(x, cfh, cfl, cn, min_d, nearest);
    finalize_kernel<<<BB, 1024, 0, stream>>>(min_d, nearest, weights, out);
}

// Round 7
// 75.614 us; speedup vs baseline: 7.8013x; 1.0876x over previous
//
#include <hip/hip_runtime.h>
#include <math.h>

#define BB 16
#define NN 4096
#define DD 128
#define KK 1024
#define NPTS (BB*NN)

typedef _Float16 half8 __attribute__((ext_vector_type(8)));
typedef float f32x16 __attribute__((ext_vector_type(16)));

static __device__ __forceinline__ uint pack2(float a, float b) {
    _Float16 ha = (_Float16)a, hb = (_Float16)b;
    unsigned short ua = __builtin_bit_cast(unsigned short, ha);
    unsigned short ub = __builtin_bit_cast(unsigned short, hb);
    return (uint)ua | ((uint)ub << 16);
}

typedef __attribute__((address_space(1))) const void as1_void;
typedef __attribute__((address_space(3))) void as3_void;
static __device__ __forceinline__ void gld16(const void* g, void* l) {
    // async global->LDS, 16B/lane; LDS dest = uniform base + lane*16 (HW rule)
    __builtin_amdgcn_global_load_lds((as1_void*)g, (as3_void*)l, 16, 0, 0);
}

// counted waits + raw barrier (loads stay in flight ACROSS barriers — T3/T4)
#define VMWAIT4 asm volatile("s_waitcnt vmcnt(4)" ::: "memory")
#define VMWAIT2 asm volatile("s_waitcnt vmcnt(2)" ::: "memory")
#define VMWAIT0 asm volatile("s_waitcnt vmcnt(0)" ::: "memory")
#define RBARRIER do { __builtin_amdgcn_s_barrier(); asm volatile("" ::: "memory"); } while (0)

// ---------------- kernel 0a: centroid squared norms (wave per row, double shfl reduce) ----------------
__global__ void cnorm_kernel(const float* __restrict__ c, float* __restrict__ cnorm) {
    const int w = threadIdx.x >> 6, lane = threadIdx.x & 63;
    const int row = blockIdx.x * 4 + w;
    float2 v = ((const float2*)(c + (size_t)row * DD))[lane];
    double s = (double)v.x * v.x + (double)v.y * v.y;
#pragma unroll
    for (int m = 1; m < 64; m <<= 1) s += __shfl_xor(s, m);
    if (lane == 0) cnorm[row] = (float)s;
}

// ---------------- kernel 0b: pre-permute centroids into per-lane B-fragment order ----------------
// Fragment (nt, c, lane) = cent row (nt*32 + (lane&31)), d in [c*16+(lane>>5)*8, +8),
// split into fp16 hi + (lo*1024), packed as uint4 (HW-verified layout, R3-R6 pass).
__global__ void cfrag_kernel(const float* __restrict__ cent,
                             uint4* __restrict__ cfh, uint4* __restrict__ cfl) {
    const int gid = blockIdx.x * 256 + threadIdx.x;   // [0, 32*8*64)
    const int nt = gid >> 9;
    const int c = (gid >> 6) & 7;
    const int lane = gid & 63;
    const int row = nt * 32 + (lane & 31);
    const int d0 = c * 16 + (lane >> 5) * 8;
    const float* src = cent + (size_t)row * DD + d0;
    float v[8];
#pragma unroll
    for (int i = 0; i < 8; ++i) v[i] = src[i];
    float lo[8];
#pragma unroll
    for (int i = 0; i < 8; ++i) {
        _Float16 h = (_Float16)v[i];
        lo[i] = (v[i] - (float)h) * 1024.f;
    }
    uint4 h4, l4;
    h4.x = pack2(v[0], v[1]); h4.y = pack2(v[2], v[3]);
    h4.z = pack2(v[4], v[5]); h4.w = pack2(v[6], v[7]);
    l4.x = pack2(lo[0], lo[1]); l4.y = pack2(lo[2], lo[3]);
    l4.z = pack2(lo[4], lo[5]); l4.w = pack2(lo[6], lo[7]);
    cfh[gid] = h4;
    cfl[gid] = l4;
}

// ---------------- kernel 1: nearest-centroid, counted-vmcnt ring pipeline ----------------
// 512 blocks x 4 waves; wave w owns rows [block*128+w*32, +32), A-frags in VGPRs.
// B staged in a 4-slot LDS ring of HALF-tiles (8 frag-rows = 8KB/slot), 64 phases.
// Phase h: ds_read slot h&3 (staged 3 phases ago), issue stage h+3 (2 gld16/wave),
// 12 MFMA, [epilogue on odd h], then s_waitcnt vmcnt(4) + raw s_barrier.
// Loads are NEVER drained to 0 in the loop; 3 stages (6 loads/wave) in flight.
// Protocol: before any wave reads stage s, every wave has executed VMWAIT(4)
// with s its oldest outstanding stage (FIFO vmcnt) and passed the barrier.
__launch_bounds__(256, 2)
__global__ void assign_mfma4(const float* __restrict__ x,
                             const uint4* __restrict__ cfh, const uint4* __restrict__ cfl,
                             const float* __restrict__ cn,
                             float* __restrict__ min_d, int* __restrict__ nearest) {
    __shared__ uint4 ring[4][8][64];   // [slot][frag-row: 0-3 hi, 4-7 lo][lane]
    __shared__ float cnS[KK];

    const int tid = threadIdx.x;
    const int lane = tid & 63;
    const int w = tid >> 6;
    const int l31 = lane & 31;
    const int lh = lane >> 5;
    const int p0 = blockIdx.x * 128 + w * 32;

    // ---- prologue: issue stages 0,1,2 into slots 0,1,2 (2 gld16 per wave each) ----
#pragma unroll
    for (int s = 0; s < 3; ++s) {
        const int snt = s >> 1, sh = s & 1;
        gld16(cfh + ((size_t)(snt * 8 + sh * 4 + w)) * 64 + lane, &ring[s][w][0]);
        gld16(cfl + ((size_t)(snt * 8 + sh * 4 + w)) * 64 + lane, &ring[s][w + 4][0]);
    }

    // cn -> LDS (read per tile in epilogue; keeps the loop free of global loads)
    ((float4*)cnS)[tid] = ((const float4*)cn)[tid];

    // A fragments (x rows) + per-row ||x||^2 (identical numerics to R3-R6)
    half8 ahi[8], alo[8];
    float xs = 0.f;
    const float4* xrow = (const float4*)(x + (size_t)(p0 + l31) * DD);
#pragma unroll
    for (int c = 0; c < 8; ++c) {
        float4 v0 = xrow[c * 4 + lh * 2];
        float4 v1 = xrow[c * 4 + lh * 2 + 1];
        float vv[8] = {v0.x, v0.y, v0.z, v0.w, v1.x, v1.y, v1.z, v1.w};
#pragma unroll
        for (int i = 0; i < 8; ++i) {
            _Float16 h = (_Float16)vv[i];
            ahi[c][i] = h;
            alo[c][i] = (_Float16)((vv[i] - (float)h) * 1024.f);
            xs = fmaf(vv[i], vv[i], xs);
        }
    }
    xs += __shfl_xor(xs, 32);   // lane l now has ||row l31||^2

    float best[16];
    int bk[16];
#pragma unroll
    for (int r = 0; r < 16; ++r) { best[r] = INFINITY; bk[r] = 0; }

    __syncthreads();   // one-time full drain: stages 0-2 + cnS + x loads all settled

// phase body: read slot, optionally issue stage S, 12 MFMA (HALF selects ahi/alo 4..7 vs 0..3)
#define MFMA3(C, BH, BL)                                                            \
    hh  = __builtin_amdgcn_mfma_f32_32x32x16_f16(ahi[C], __builtin_bit_cast(half8, BH), hh, 0, 0, 0);  \
    cr0 = __builtin_amdgcn_mfma_f32_32x32x16_f16(ahi[C], __builtin_bit_cast(half8, BL), cr0, 0, 0, 0); \
    cr1 = __builtin_amdgcn_mfma_f32_32x32x16_f16(alo[C], __builtin_bit_cast(half8, BH), cr1, 0, 0, 0);

#define DO_PHASE(HALF, NT, SSTAGE, DOSTAGE)                                         \
    {                                                                               \
        const int slot_ = (2 * (NT) + (HALF)) & 3;                                  \
        uint4 bh0 = ring[slot_][0][lane], bh1 = ring[slot_][1][lane];               \
        uint4 bh2 = ring[slot_][2][lane], bh3 = ring[slot_][3][lane];               \
        uint4 bl0 = ring[slot_][4][lane], bl1 = ring[slot_][5][lane];               \
        uint4 bl2 = ring[slot_][6][lane], bl3 = ring[slot_][7][lane];               \
        if (DOSTAGE) {                                                              \
            const int s_ = (SSTAGE);                                                \
            const int snt_ = s_ >> 1, sh_ = s_ & 1, sslot_ = s_ & 3;                \
            gld16(cfh + ((size_t)(snt_ * 8 + sh_ * 4 + w)) * 64 + lane, &ring[sslot_][w][0]);     \
            gld16(cfl + ((size_t)(snt_ * 8 + sh_ * 4 + w)) * 64 + lane, &ring[sslot_][w + 4][0]); \
        }                                                                           \
        __builtin_amdgcn_s_setprio(1);                                              \
        MFMA3((HALF)*4 + 0, bh0, bl0)                                               \
        MFMA3((HALF)*4 + 1, bh1, bl1)                                               \
        MFMA3((HALF)*4 + 2, bh2, bl2)                                               \
        MFMA3((HALF)*4 + 3, bh3, bl3)                                               \
        __builtin_amdgcn_s_setprio(0);                                              \
    }

#define EPILOGUE(NT)                                                                \
    {                                                                               \
        const float cnv = cnS[(NT) * 32 + l31];                                     \
        const int kcur = (NT) * 32 + l31;                                           \
        _Pragma("unroll")                                                           \
        for (int r = 0; r < 16; ++r) {                                              \
            float v = cnv - 2.f * hh[r] - 0.001953125f * (cr0[r] + cr1[r]);         \
            if (v < best[r]) { best[r] = v; bk[r] = kcur; }                         \
        }                                                                           \
    }

#pragma unroll 1
    for (int nt = 0; nt < 30; ++nt) {
        f32x16 hh, cr0, cr1;
#pragma unroll
        for (int i = 0; i < 16; ++i) { hh[i] = 0.f; cr0[i] = 0.f; cr1[i] = 0.f; }
        DO_PHASE(0, nt, 2 * nt + 3, 1)
        VMWAIT4; RBARRIER;
        DO_PHASE(1, nt, 2 * nt + 4, 1)
        EPILOGUE(nt)
        VMWAIT4; RBARRIER;
    }
    {   // nt = 30: stage 63 is the last issue; drain schedule 4 -> 2
        f32x16 hh, cr0, cr1;
#pragma unroll
        for (int i = 0; i < 16; ++i) { hh[i] = 0.f; cr0[i] = 0.f; cr1[i] = 0.f; }
        DO_PHASE(0, 30, 63, 1)
        VMWAIT4; RBARRIER;
        DO_PHASE(1, 30, 0, 0)
        EPILOGUE(30)
        VMWAIT2; RBARRIER;
    }
    {   // nt = 31: no more staging; 2 -> 0 -> done
        f32x16 hh, cr0, cr1;
#pragma unroll
        for (int i = 0; i < 16; ++i) { hh[i] = 0.f; cr0[i] = 0.f; cr1[i] = 0.f; }
        DO_PHASE(0, 31, 0, 0)
        VMWAIT0; RBARRIER;
        DO_PHASE(1, 31, 0, 0)
        EPILOGUE(31)
    }
#undef DO_PHASE
#undef MFMA3
#undef EPILOGUE

    // cross-lane argmin over the 32 centroid columns (masks < 32 stay in half-wave)
#pragma unroll
    for (int r = 0; r < 16; ++r) {
        float bv = best[r]; int bi = bk[r];
#pragma unroll
        for (int m = 1; m < 32; m <<= 1) {
            float ov = __shfl_xor(bv, m);
            int oi = __shfl_xor(bi, m);
            if (ov < bv || (ov == bv && oi < bi)) { bv = ov; bi = oi; }
        }
        best[r] = bv; bk[r] = bi;
    }

    // gather ||x||^2 for this half's output rows (static shfl indices, all lanes)
    float xnv[16];
#pragma unroll
    for (int r = 0; r < 16; ++r)
        xnv[r] = __shfl(xs, (r & 3) + 8 * (r >> 2) + 4 * lh);

    if (l31 == 0) {
#pragma unroll
        for (int r = 0; r < 16; ++r) {
            int m = (r & 3) + 8 * (r >> 2) + 4 * lh;   // D-layout row (HW-verified)
            float sq = xnv[r] + best[r];
            min_d[p0 + m] = sqrtf(fmaxf(sq, 0.f));
            nearest[p0 + m] = bk[r];
        }
    }
}

// ---------------- kernel 2: per-batch stats + histogram + normalize (1024 threads) ----------------
__global__ void finalize_kernel(const float* __restrict__ min_d, const int* __restrict__ nearest,
                                const float* __restrict__ weights, float* __restrict__ out) {
    __shared__ float red[1024];
    __shared__ int hist[KK];
    __shared__ float bc[2];  // mean, thr
    const int b = blockIdx.x;
    const int tid = threadIdx.x;
    const float* md = min_d + (size_t)b * NN;
    const int* nr = nearest + (size_t)b * NN;

    // pass A: mean (two-pass std to match numpy numerics)
    float s = 0.f;
#pragma unroll
    for (int j = 0; j < NN / 1024; ++j) s += md[tid + 1024 * j];
    red[tid] = s;
    __syncthreads();
    for (int off = 512; off > 0; off >>= 1) {
        if (tid < off) red[tid] += red[tid + off];
        __syncthreads();
    }
    if (tid == 0) bc[0] = red[0] / (float)NN;
    __syncthreads();
    const float mean = bc[0];

    // pass B: sum of squared deviations -> thr = mean + std(ddof=1)
    float ss = 0.f;
#pragma unroll
    for (int j = 0; j < NN / 1024; ++j) {
        float v = md[tid + 1024 * j] - mean;
        ss += v * v;
    }
    red[tid] = ss;
    __syncthreads();
    for (int off = 512; off > 0; off >>= 1) {
        if (tid < off) red[tid] += red[tid + off];
        __syncthreads();
    }
    if (tid == 0) bc[1] = mean + sqrtf(red[0] / (float)(NN - 1));

    // histogram of masked assignments
    hist[tid] = 0;
    __syncthreads();
    const float thr = bc[1];
#pragma unroll
    for (int j = 0; j < NN / 1024; ++j) {
        int i = tid + 1024 * j;
        if (md[i] < thr) atomicAdd(&hist[nr[i]], 1);
    }
    __syncthreads();

    // asmk = counts*weights; L2-normalize the row (one k per thread)
    const float a = (float)hist[tid] * weights[tid];
    red[tid] = a * a;
    __syncthreads();
    for (int off = 512; off > 0; off >>= 1) {
        if (tid < off) red[tid] += red[tid + off];
        __syncthreads();
    }
    const float norm = sqrtf(red[0]);
    const float scale = 1.f / fmaxf(norm, 1e-12f);
    out[(size_t)b * KK + tid] = a * scale;
}

extern "C" void kernel_launch(void* const* d_in, const int* in_sizes, int n_in,
                              void* d_out, int out_size, void* d_ws, size_t ws_size,
                              hipStream_t stream) {
    const float* x = (const float*)d_in[0];
    const float* cent = (const float*)d_in[1];
    const float* weights = (const float*)d_in[2];
    float* out = (float*)d_out;

    char* ws = (char*)d_ws;
    float* min_d   = (float*)(ws + 0);
    int*   nearest = (int*)  (ws + 262144);
    float* cn      = (float*)(ws + 524288);
    uint4* cfh     = (uint4*)(ws + 528384);
    uint4* cfl     = (uint4*)(ws + 790528);

    cnorm_kernel<<<KK / 4, 256, 0, stream>>>(cent, cn);
    cfrag_kernel<<<64, 256, 0, stream>>>(cent, cfh, cfl);
    assign_mfma4<<<NPTS / 128, 256, 0, stream>>>(x, cfh, cfl, cn, min_d, nearest);
    finalize_kernel<<<BB, 1024, 0, stream>>>(min_d, nearest, weights, out);
}